// Round 1
// baseline (491.153 us; speedup 1.0000x reference)
//
#include <hip/hip_runtime.h>
#include <math.h>

// Problem constants (B,T,D,H,L from the reference)
#define BB 4
#define TT 2048
#define DD 512
#define HH 8
#define NLAYER 2
#define EPS 1e-5f
#define SCALE 0.125f            // dh^-0.5, dh=64

#define NT 64                   // blocks per batch for masked-sum stage 1
#define ROWS_PER_WAVE 8         // TT / (NT*4 waves)
#define NWTILES 256             // NT * 4 wave-tiles per batch

// ---------------------------------------------------------------------------
// Stage 1: masked sum over T of LayerNorm(x_key) with the phase's gamma/beta.
// One wave per 8 rows; per-wave partial sums -> partial[b][wtile][d].
// Deterministic (no atomics).
// ---------------------------------------------------------------------------
__global__ __launch_bounds__(256) void ln_masked_sum_kernel(
    const float* __restrict__ x,      // (B,T,D)
    const int*   __restrict__ kpm,    // (B,T)  nonzero = masked out
    const float* __restrict__ gamma,  // (D)
    const float* __restrict__ beta,   // (D)
    float* __restrict__ partial)      // (B, NWTILES, D)
{
  const int b    = blockIdx.x / NT;
  const int tile = blockIdx.x % NT;
  const int wave = threadIdx.x >> 6;
  const int lane = threadIdx.x & 63;
  const int wtile = tile * 4 + wave;
  const int row0  = wtile * ROWS_PER_WAVE;

  // per-lane d indices: d = c*256 + lane*4 + k
  float4 g0 = *reinterpret_cast<const float4*>(gamma + lane * 4);
  float4 g1 = *reinterpret_cast<const float4*>(gamma + 256 + lane * 4);
  float4 be0 = *reinterpret_cast<const float4*>(beta + lane * 4);
  float4 be1 = *reinterpret_cast<const float4*>(beta + 256 + lane * 4);
  float gv[8] = {g0.x, g0.y, g0.z, g0.w, g1.x, g1.y, g1.z, g1.w};
  float bv[8] = {be0.x, be0.y, be0.z, be0.w, be1.x, be1.y, be1.z, be1.w};

  float acc[8] = {0.f, 0.f, 0.f, 0.f, 0.f, 0.f, 0.f, 0.f};

  for (int r = 0; r < ROWS_PER_WAVE; ++r) {
    const int t = row0 + r;
    const float* xr = x + ((size_t)b * TT + t) * DD;
    float4 a0 = *reinterpret_cast<const float4*>(xr + lane * 4);
    float4 a1 = *reinterpret_cast<const float4*>(xr + 256 + lane * 4);
    float v[8] = {a0.x, a0.y, a0.z, a0.w, a1.x, a1.y, a1.z, a1.w};
    float s = 0.f, s2 = 0.f;
#pragma unroll
    for (int k = 0; k < 8; ++k) { s += v[k]; s2 += v[k] * v[k]; }
#pragma unroll
    for (int off = 32; off > 0; off >>= 1) {
      s  += __shfl_xor(s, off);
      s2 += __shfl_xor(s2, off);
    }
    const float mean = s * (1.f / (float)DD);
    const float var  = s2 * (1.f / (float)DD) - mean * mean;
    const float rstd = rsqrtf(var + EPS);
    if (kpm[b * TT + t] == 0) {   // wave-uniform branch
#pragma unroll
      for (int k = 0; k < 8; ++k) acc[k] += (v[k] - mean) * rstd * gv[k] + bv[k];
    }
  }

  float* p = partial + ((size_t)b * NWTILES + wtile) * DD;
  *reinterpret_cast<float4*>(p + lane * 4)       = make_float4(acc[0], acc[1], acc[2], acc[3]);
  *reinterpret_cast<float4*>(p + 256 + lane * 4) = make_float4(acc[4], acc[5], acc[6], acc[7]);
}

// ---------------------------------------------------------------------------
// Stage 2 (tiny): reduce partials -> nsum; valid count; ksum = Wk*nsum;
// m[h][d] = (scale/valid) * sum_j Wq[h*64+j][d] * ksum[h*64+j]; flag = !all_masked
// One block per batch element.
// ---------------------------------------------------------------------------
__global__ __launch_bounds__(256) void compute_m_kernel(
    const float* __restrict__ partial,  // (B,NWTILES,D)
    const int*   __restrict__ kpm,      // (B,T)
    const float* __restrict__ Wk,       // (D,D) row o, col d  (layer slice)
    const float* __restrict__ Wq,       // (D,D)
    float* __restrict__ m,              // (B,H,D)
    float* __restrict__ flag)           // (B)
{
  const int b   = blockIdx.x;
  const int tid = threadIdx.x;
  __shared__ float nsum[DD];
  __shared__ float ks[DD];
  __shared__ int cshare[256];

  for (int d = tid; d < DD; d += 256) {
    float s = 0.f;
    const float* p = partial + (size_t)b * NWTILES * DD + d;
    for (int w = 0; w < NWTILES; ++w) s += p[(size_t)w * DD];
    nsum[d] = s;
  }
  int cnt = 0;
  for (int t = tid; t < TT; t += 256) cnt += (kpm[b * TT + t] == 0) ? 1 : 0;
  cshare[tid] = cnt;
  __syncthreads();
  for (int s = 128; s > 0; s >>= 1) {
    if (tid < s) cshare[tid] += cshare[tid + s];
    __syncthreads();
  }
  const int validcnt = cshare[0];
  if (tid == 0) flag[b] = (validcnt == 0) ? 0.f : 1.f;
  const float fac = SCALE / fmaxf((float)validcnt, 1.f);

  // ksum[o] = nsum . Wk[o,:]
  for (int o = tid; o < DD; o += 256) {
    float s = 0.f;
    const float* wr = Wk + (size_t)o * DD;
    for (int d2 = 0; d2 < DD; ++d2) s += nsum[d2] * wr[d2];
    ks[o] = s;
  }
  __syncthreads();

  // m[h][d] = fac * sum_j Wq[h*64+j][d] * ks[h*64+j]
  for (int idx = tid; idx < HH * DD; idx += 256) {
    const int h = idx >> 9;          // idx / 512
    const int d = idx & (DD - 1);
    const float* wq = Wq + (size_t)(h * 64) * DD + d;
    float s = 0.f;
#pragma unroll 8
    for (int j = 0; j < 64; ++j) s += wq[(size_t)j * DD] * ks[h * 64 + j];
    m[((size_t)b * HH + h) * DD + d] = s * fac;
  }
}

// ---------------------------------------------------------------------------
// Stage 3: per-row update of the query tensor.
// One wave per row: LN(x_row), rel[h] = n . m[b,h,:], gate MLP (redundant on
// all lanes), out = x * (1 + flag*sigmoid(z)).
// ---------------------------------------------------------------------------
__global__ __launch_bounds__(256) void update_kernel(
    const float* __restrict__ xin,    // (B,T,D)
    const float* __restrict__ gamma,  // (D)
    const float* __restrict__ beta,   // (D)
    const float* __restrict__ m,      // (B,H,D)
    const float* __restrict__ flag,   // (B)
    const float* __restrict__ W1,     // (16,8)
    const float* __restrict__ b1,     // (16)
    const float* __restrict__ W2,     // (16)
    const float* __restrict__ b2,     // (1)
    float* __restrict__ xout)         // (B,T,D)
{
  const int row  = blockIdx.x * 4 + (threadIdx.x >> 6);
  const int lane = threadIdx.x & 63;
  const int b    = row >> 11;        // row / TT

  const float* xr = xin + (size_t)row * DD;
  float4 a0 = *reinterpret_cast<const float4*>(xr + lane * 4);
  float4 a1 = *reinterpret_cast<const float4*>(xr + 256 + lane * 4);
  float v[8] = {a0.x, a0.y, a0.z, a0.w, a1.x, a1.y, a1.z, a1.w};

  float4 g0 = *reinterpret_cast<const float4*>(gamma + lane * 4);
  float4 g1 = *reinterpret_cast<const float4*>(gamma + 256 + lane * 4);
  float4 be0 = *reinterpret_cast<const float4*>(beta + lane * 4);
  float4 be1 = *reinterpret_cast<const float4*>(beta + 256 + lane * 4);
  float gv[8] = {g0.x, g0.y, g0.z, g0.w, g1.x, g1.y, g1.z, g1.w};
  float bv[8] = {be0.x, be0.y, be0.z, be0.w, be1.x, be1.y, be1.z, be1.w};

  float s = 0.f, s2 = 0.f;
#pragma unroll
  for (int k = 0; k < 8; ++k) { s += v[k]; s2 += v[k] * v[k]; }
#pragma unroll
  for (int off = 32; off > 0; off >>= 1) {
    s  += __shfl_xor(s, off);
    s2 += __shfl_xor(s2, off);
  }
  const float mean = s * (1.f / (float)DD);
  const float var  = s2 * (1.f / (float)DD) - mean * mean;
  const float rstd = rsqrtf(var + EPS);

  float n[8];
#pragma unroll
  for (int k = 0; k < 8; ++k) n[k] = (v[k] - mean) * rstd * gv[k] + bv[k];

  const float* mb = m + (size_t)b * HH * DD;
  float rel[HH];
#pragma unroll
  for (int h = 0; h < HH; ++h) {
    const float* mh = mb + (size_t)h * DD;
    float4 m0 = *reinterpret_cast<const float4*>(mh + lane * 4);
    float4 m1 = *reinterpret_cast<const float4*>(mh + 256 + lane * 4);
    float p = n[0] * m0.x + n[1] * m0.y + n[2] * m0.z + n[3] * m0.w +
              n[4] * m1.x + n[5] * m1.y + n[6] * m1.z + n[7] * m1.w;
#pragma unroll
    for (int off = 32; off > 0; off >>= 1) p += __shfl_xor(p, off);
    rel[h] = p;   // all lanes hold the full dot product
  }

  // gate MLP (all lanes redundantly; tiny)
  float z = b2[0];
#pragma unroll
  for (int e = 0; e < 16; ++e) {
    float h1 = b1[e];
#pragma unroll
    for (int h = 0; h < HH; ++h) h1 += rel[h] * W1[e * HH + h];
    z += fmaxf(h1, 0.f) * W2[e];
  }
  const float gate = flag[b] * (1.f / (1.f + expf(-z)));
  const float sc = 1.f + gate;

  float* orow = xout + (size_t)row * DD;
  *reinterpret_cast<float4*>(orow + lane * 4) =
      make_float4(v[0] * sc, v[1] * sc, v[2] * sc, v[3] * sc);
  *reinterpret_cast<float4*>(orow + 256 + lane * 4) =
      make_float4(v[4] * sc, v[5] * sc, v[6] * sc, v[7] * sc);
}

// ---------------------------------------------------------------------------
extern "C" void kernel_launch(void* const* d_in, const int* in_sizes, int n_in,
                              void* d_out, int out_size, void* d_ws, size_t ws_size,
                              hipStream_t stream) {
  const float* x_vid = (const float*)d_in[0];
  const float* x_aud = (const float*)d_in[1];
  const int* vid_kpm = (const int*)d_in[2];
  const int* aud_kpm = (const int*)d_in[3];
  const float* Wq_vid         = (const float*)d_in[4];
  const float* Wk_aud_for_vid = (const float*)d_in[5];
  const float* Wq_aud         = (const float*)d_in[6];
  const float* Wk_vid_for_aud = (const float*)d_in[7];
  const float* vg_W1 = (const float*)d_in[8];
  const float* vg_b1 = (const float*)d_in[9];
  const float* vg_W2 = (const float*)d_in[10];
  const float* vg_b2 = (const float*)d_in[11];
  const float* ag_W1 = (const float*)d_in[12];
  const float* ag_b1 = (const float*)d_in[13];
  const float* ag_W2 = (const float*)d_in[14];
  const float* ag_b2 = (const float*)d_in[15];
  const float* vid_ln_g = (const float*)d_in[16];
  const float* vid_ln_b = (const float*)d_in[17];
  const float* aud_ln_g = (const float*)d_in[18];
  const float* aud_ln_b = (const float*)d_in[19];

  const size_t BTD = (size_t)BB * TT * DD;
  float* xv = (float*)d_out;        // working/output x_vid
  float* xa = xv + BTD;             // working/output x_aud

  float* partial = (float*)d_ws;                        // B*NWTILES*D floats (2 MB)
  float* m       = partial + (size_t)BB * NWTILES * DD; // B*H*D floats (64 KB)
  float* flg     = m + (size_t)BB * HH * DD;            // B floats

  const size_t WW = (size_t)DD * DD;  // per-layer weight matrix stride

  for (int i = 0; i < NLAYER; ++i) {
    const float* srcV = (i == 0) ? x_vid : xv;
    const float* srcA = (i == 0) ? x_aud : xa;

    // --- Phase A: vid gated by attn to aud; vid_ln applied to BOTH sides ---
    ln_masked_sum_kernel<<<BB * NT, 256, 0, stream>>>(
        srcA, aud_kpm, vid_ln_g + (size_t)i * DD, vid_ln_b + (size_t)i * DD, partial);
    compute_m_kernel<<<BB, 256, 0, stream>>>(
        partial, aud_kpm, Wk_aud_for_vid + (size_t)i * WW, Wq_vid + (size_t)i * WW, m, flg);
    update_kernel<<<(BB * TT) / 4, 256, 0, stream>>>(
        srcV, vid_ln_g + (size_t)i * DD, vid_ln_b + (size_t)i * DD, m, flg,
        vg_W1 + (size_t)i * 16 * HH, vg_b1 + (size_t)i * 16,
        vg_W2 + (size_t)i * 16, vg_b2 + i, xv);

    // --- Phase B: aud gated by attn to UPDATED vid; aud_ln on BOTH sides ---
    ln_masked_sum_kernel<<<BB * NT, 256, 0, stream>>>(
        xv, vid_kpm, aud_ln_g + (size_t)i * DD, aud_ln_b + (size_t)i * DD, partial);
    compute_m_kernel<<<BB, 256, 0, stream>>>(
        partial, vid_kpm, Wk_vid_for_aud + (size_t)i * WW, Wq_aud + (size_t)i * WW, m, flg);
    update_kernel<<<(BB * TT) / 4, 256, 0, stream>>>(
        srcA, aud_ln_g + (size_t)i * DD, aud_ln_b + (size_t)i * DD, m, flg,
        ag_W1 + (size_t)i * 16 * HH, ag_b1 + (size_t)i * 16,
        ag_W2 + (size_t)i * 16, ag_b2 + i, xa);
  }
}

// Round 2
// 136.945 us; speedup vs baseline: 3.5865x; 3.5865x over previous
//
#include <hip/hip_runtime.h>
#include <math.h>

// Problem constants (B,T,D,H,L from the reference)
#define BB 4
#define TT 2048
#define DD 512
#define HH 8
#define NLAYER 2
#define EPS 1e-5f
#define SCALE 0.125f            // dh^-0.5, dh=64

#define NT 64                   // blocks per batch for masked-sum stage 1
#define ROWS_PER_WAVE 8         // TT / (NT*4 waves)

// ---------------------------------------------------------------------------
// Stage 1: masked sum over T of LayerNorm(x_key). One wave per 8 rows; the
// block's 4 waves LDS-reduce into one partial tile -> partial[b][tile][d].
// Deterministic (no atomics).
// ---------------------------------------------------------------------------
__global__ __launch_bounds__(256) void ln_masked_sum_kernel(
    const float* __restrict__ x,      // (B,T,D)
    const int*   __restrict__ kpm,    // (B,T)  nonzero = masked out
    const float* __restrict__ gamma,  // (D)
    const float* __restrict__ beta,   // (D)
    float* __restrict__ partial)      // (B, NT, D)
{
  const int b    = blockIdx.x / NT;
  const int tile = blockIdx.x % NT;
  const int wave = threadIdx.x >> 6;
  const int lane = threadIdx.x & 63;
  const int row0 = (tile * 4 + wave) * ROWS_PER_WAVE;

  __shared__ float lds[4][DD];

  float4 g0 = *reinterpret_cast<const float4*>(gamma + lane * 4);
  float4 g1 = *reinterpret_cast<const float4*>(gamma + 256 + lane * 4);
  float4 be0 = *reinterpret_cast<const float4*>(beta + lane * 4);
  float4 be1 = *reinterpret_cast<const float4*>(beta + 256 + lane * 4);
  float gv[8] = {g0.x, g0.y, g0.z, g0.w, g1.x, g1.y, g1.z, g1.w};
  float bv[8] = {be0.x, be0.y, be0.z, be0.w, be1.x, be1.y, be1.z, be1.w};

  float acc[8] = {0.f, 0.f, 0.f, 0.f, 0.f, 0.f, 0.f, 0.f};

  for (int r = 0; r < ROWS_PER_WAVE; ++r) {
    const int t = row0 + r;
    const float* xr = x + ((size_t)b * TT + t) * DD;
    float4 a0 = *reinterpret_cast<const float4*>(xr + lane * 4);
    float4 a1 = *reinterpret_cast<const float4*>(xr + 256 + lane * 4);
    float v[8] = {a0.x, a0.y, a0.z, a0.w, a1.x, a1.y, a1.z, a1.w};
    float s = 0.f, s2 = 0.f;
#pragma unroll
    for (int k = 0; k < 8; ++k) { s += v[k]; s2 += v[k] * v[k]; }
#pragma unroll
    for (int off = 32; off > 0; off >>= 1) {
      s  += __shfl_xor(s, off);
      s2 += __shfl_xor(s2, off);
    }
    const float mean = s * (1.f / (float)DD);
    const float var  = s2 * (1.f / (float)DD) - mean * mean;
    const float rstd = rsqrtf(var + EPS);
    if (kpm[b * TT + t] == 0) {   // wave-uniform branch
#pragma unroll
      for (int k = 0; k < 8; ++k) acc[k] += (v[k] - mean) * rstd * gv[k] + bv[k];
    }
  }

#pragma unroll
  for (int k = 0; k < 4; ++k) {
    lds[wave][lane * 4 + k]       = acc[k];
    lds[wave][256 + lane * 4 + k] = acc[4 + k];
  }
  __syncthreads();

  // 256 threads: d = tid and tid+256
  const int tid = threadIdx.x;
  float s0 = lds[0][tid] + lds[1][tid] + lds[2][tid] + lds[3][tid];
  float s1 = lds[0][tid + 256] + lds[1][tid + 256] + lds[2][tid + 256] + lds[3][tid + 256];
  float* p = partial + ((size_t)b * NT + tile) * DD;
  p[tid]       = s0;
  p[tid + 256] = s1;
}

// ---------------------------------------------------------------------------
// Stage 2a: nsum[b][d] = sum over NT partial tiles; dchunk 0 also computes
// validcnt -> fac[b] = SCALE/max(valid,1), flag[b].
// Grid: BB*8 blocks (b, dchunk of 64 d's), 256 threads.
// ---------------------------------------------------------------------------
__global__ __launch_bounds__(256) void reduce_nsum_kernel(
    const float* __restrict__ partial,  // (B,NT,D)
    const int*   __restrict__ kpm,      // (B,T)
    float* __restrict__ nsum,           // (B,D)
    float* __restrict__ fac,            // (B)
    float* __restrict__ flag)           // (B)
{
  const int b      = blockIdx.x >> 3;
  const int dchunk = blockIdx.x & 7;
  const int tid    = threadIdx.x;
  const int dl     = tid & 63;              // d within chunk
  const int grp    = tid >> 6;              // 0..3 -> wtile quarter
  const int d      = dchunk * 64 + dl;

  __shared__ float lds[4][64];
  __shared__ float csh[4];

  float s = 0.f;
  const float* p = partial + (size_t)b * NT * DD + d;
#pragma unroll 4
  for (int w = grp * 16; w < grp * 16 + 16; ++w) s += p[(size_t)w * DD];
  lds[grp][dl] = s;
  __syncthreads();
  if (grp == 0) {
    float t = lds[0][dl] + lds[1][dl] + lds[2][dl] + lds[3][dl];
    nsum[(size_t)b * DD + d] = t;
  }

  if (dchunk == 0) {
    int cnt = 0;
    for (int t = tid; t < TT; t += 256) cnt += (kpm[b * TT + t] == 0) ? 1 : 0;
#pragma unroll
    for (int off = 32; off > 0; off >>= 1) cnt += __shfl_xor(cnt, off);
    if ((tid & 63) == 0) csh[tid >> 6] = (float)cnt;
    __syncthreads();
    if (tid == 0) {
      float vc = csh[0] + csh[1] + csh[2] + csh[3];
      flag[b] = (vc > 0.f) ? 1.f : 0.f;
      fac[b]  = SCALE / fmaxf(vc, 1.f);
    }
  }
}

// ---------------------------------------------------------------------------
// Stage 2b: ks[b][o] = Wk[o,:] . nsum[b,:].  One WAVE per (b,o).
// Grid: BB*DD/4 = 512 blocks, 256 threads (4 waves).
// ---------------------------------------------------------------------------
__global__ __launch_bounds__(256) void ksum_kernel(
    const float* __restrict__ nsum,   // (B,D)
    const float* __restrict__ Wk,     // (D,D) layer slice
    float* __restrict__ ks)           // (B,D)
{
  const int wid  = blockIdx.x * 4 + (threadIdx.x >> 6);
  const int b    = wid >> 9;          // 512 outputs per batch
  const int o    = wid & (DD - 1);
  const int lane = threadIdx.x & 63;

  const float* wr = Wk + (size_t)o * DD + lane * 8;
  const float* nr = nsum + (size_t)b * DD + lane * 8;
  float4 w0 = *reinterpret_cast<const float4*>(wr);
  float4 w1 = *reinterpret_cast<const float4*>(wr + 4);
  float4 n0 = *reinterpret_cast<const float4*>(nr);
  float4 n1 = *reinterpret_cast<const float4*>(nr + 4);
  float s = w0.x * n0.x + w0.y * n0.y + w0.z * n0.z + w0.w * n0.w +
            w1.x * n1.x + w1.y * n1.y + w1.z * n1.z + w1.w * n1.w;
#pragma unroll
  for (int off = 32; off > 0; off >>= 1) s += __shfl_xor(s, off);
  if (lane == 0) ks[(size_t)b * DD + o] = s;
}

// ---------------------------------------------------------------------------
// Stage 2c: m[b,h,d] = fac[b] * sum_j Wq[h*64+j][d] * ks[b][h*64+j]
// Grid: BB*HH = 32 blocks, 256 threads (each thread: d=tid and d=tid+256).
// ---------------------------------------------------------------------------
__global__ __launch_bounds__(256) void m_kernel(
    const float* __restrict__ ks,     // (B,D)
    const float* __restrict__ fac,    // (B)
    const float* __restrict__ Wq,     // (D,D) layer slice
    float* __restrict__ m)            // (B,H,D)
{
  const int b = blockIdx.x >> 3;
  const int h = blockIdx.x & 7;
  const int tid = threadIdx.x;

  __shared__ float w[64];
  if (tid < 64) w[tid] = ks[(size_t)b * DD + h * 64 + tid] * fac[b];
  __syncthreads();

  float s0 = 0.f, s1 = 0.f;
  const float* base = Wq + (size_t)(h * 64) * DD;
#pragma unroll 8
  for (int j = 0; j < 64; ++j) {
    const float* row = base + (size_t)j * DD;
    s0 += row[tid] * w[j];
    s1 += row[tid + 256] * w[j];
  }
  float* mo = m + ((size_t)b * HH + h) * DD;
  mo[tid]       = s0;
  mo[tid + 256] = s1;
}

// ---------------------------------------------------------------------------
// Stage 3: per-row update of the query tensor.
// One wave per row: LN(x_row), rel[h] = n . m[b,h,:], gate MLP (redundant on
// all lanes), out = x * (1 + flag*sigmoid(z)).
// ---------------------------------------------------------------------------
__global__ __launch_bounds__(256) void update_kernel(
    const float* __restrict__ xin,    // (B,T,D)
    const float* __restrict__ gamma,  // (D)
    const float* __restrict__ beta,   // (D)
    const float* __restrict__ m,      // (B,H,D)
    const float* __restrict__ flag,   // (B)
    const float* __restrict__ W1,     // (16,8)
    const float* __restrict__ b1,     // (16)
    const float* __restrict__ W2,     // (16)
    const float* __restrict__ b2,     // (1)
    float* __restrict__ xout)         // (B,T,D)
{
  const int row  = blockIdx.x * 4 + (threadIdx.x >> 6);
  const int lane = threadIdx.x & 63;
  const int b    = row >> 11;        // row / TT

  const float* xr = xin + (size_t)row * DD;
  float4 a0 = *reinterpret_cast<const float4*>(xr + lane * 4);
  float4 a1 = *reinterpret_cast<const float4*>(xr + 256 + lane * 4);
  float v[8] = {a0.x, a0.y, a0.z, a0.w, a1.x, a1.y, a1.z, a1.w};

  float4 g0 = *reinterpret_cast<const float4*>(gamma + lane * 4);
  float4 g1 = *reinterpret_cast<const float4*>(gamma + 256 + lane * 4);
  float4 be0 = *reinterpret_cast<const float4*>(beta + lane * 4);
  float4 be1 = *reinterpret_cast<const float4*>(beta + 256 + lane * 4);
  float gv[8] = {g0.x, g0.y, g0.z, g0.w, g1.x, g1.y, g1.z, g1.w};
  float bv[8] = {be0.x, be0.y, be0.z, be0.w, be1.x, be1.y, be1.z, be1.w};

  float s = 0.f, s2 = 0.f;
#pragma unroll
  for (int k = 0; k < 8; ++k) { s += v[k]; s2 += v[k] * v[k]; }
#pragma unroll
  for (int off = 32; off > 0; off >>= 1) {
    s  += __shfl_xor(s, off);
    s2 += __shfl_xor(s2, off);
  }
  const float mean = s * (1.f / (float)DD);
  const float var  = s2 * (1.f / (float)DD) - mean * mean;
  const float rstd = rsqrtf(var + EPS);

  float n[8];
#pragma unroll
  for (int k = 0; k < 8; ++k) n[k] = (v[k] - mean) * rstd * gv[k] + bv[k];

  const float* mb = m + (size_t)b * HH * DD;
  float rel[HH];
#pragma unroll
  for (int h = 0; h < HH; ++h) {
    const float* mh = mb + (size_t)h * DD;
    float4 m0 = *reinterpret_cast<const float4*>(mh + lane * 4);
    float4 m1 = *reinterpret_cast<const float4*>(mh + 256 + lane * 4);
    float p = n[0] * m0.x + n[1] * m0.y + n[2] * m0.z + n[3] * m0.w +
              n[4] * m1.x + n[5] * m1.y + n[6] * m1.z + n[7] * m1.w;
#pragma unroll
    for (int off = 32; off > 0; off >>= 1) p += __shfl_xor(p, off);
    rel[h] = p;   // all lanes hold the full dot product
  }

  // gate MLP (all lanes redundantly; tiny)
  float z = b2[0];
#pragma unroll
  for (int e = 0; e < 16; ++e) {
    float h1 = b1[e];
#pragma unroll
    for (int h = 0; h < HH; ++h) h1 += rel[h] * W1[e * HH + h];
    z += fmaxf(h1, 0.f) * W2[e];
  }
  const float gate = flag[b] * (1.f / (1.f + expf(-z)));
  const float sc = 1.f + gate;

  float* orow = xout + (size_t)row * DD;
  *reinterpret_cast<float4*>(orow + lane * 4) =
      make_float4(v[0] * sc, v[1] * sc, v[2] * sc, v[3] * sc);
  *reinterpret_cast<float4*>(orow + 256 + lane * 4) =
      make_float4(v[4] * sc, v[5] * sc, v[6] * sc, v[7] * sc);
}

// ---------------------------------------------------------------------------
extern "C" void kernel_launch(void* const* d_in, const int* in_sizes, int n_in,
                              void* d_out, int out_size, void* d_ws, size_t ws_size,
                              hipStream_t stream) {
  const float* x_vid = (const float*)d_in[0];
  const float* x_aud = (const float*)d_in[1];
  const int* vid_kpm = (const int*)d_in[2];
  const int* aud_kpm = (const int*)d_in[3];
  const float* Wq_vid         = (const float*)d_in[4];
  const float* Wk_aud_for_vid = (const float*)d_in[5];
  const float* Wq_aud         = (const float*)d_in[6];
  const float* Wk_vid_for_aud = (const float*)d_in[7];
  const float* vg_W1 = (const float*)d_in[8];
  const float* vg_b1 = (const float*)d_in[9];
  const float* vg_W2 = (const float*)d_in[10];
  const float* vg_b2 = (const float*)d_in[11];
  const float* ag_W1 = (const float*)d_in[12];
  const float* ag_b1 = (const float*)d_in[13];
  const float* ag_W2 = (const float*)d_in[14];
  const float* ag_b2 = (const float*)d_in[15];
  const float* vid_ln_g = (const float*)d_in[16];
  const float* vid_ln_b = (const float*)d_in[17];
  const float* aud_ln_g = (const float*)d_in[18];
  const float* aud_ln_b = (const float*)d_in[19];

  const size_t BTD = (size_t)BB * TT * DD;
  float* xv = (float*)d_out;        // working/output x_vid
  float* xa = xv + BTD;             // working/output x_aud

  float* partial = (float*)d_ws;                        // B*NT*D floats (512 KB)
  float* nsum    = partial + (size_t)BB * NT * DD;      // B*D
  float* ks      = nsum + (size_t)BB * DD;              // B*D
  float* m       = ks + (size_t)BB * DD;                // B*H*D
  float* fac     = m + (size_t)BB * HH * DD;            // B
  float* flg     = fac + BB;                            // B

  const size_t WW = (size_t)DD * DD;  // per-layer weight matrix stride

  for (int i = 0; i < NLAYER; ++i) {
    const float* srcV = (i == 0) ? x_vid : xv;
    const float* srcA = (i == 0) ? x_aud : xa;

    // --- Phase A: vid gated by attn to aud; vid_ln applied to BOTH sides ---
    ln_masked_sum_kernel<<<BB * NT, 256, 0, stream>>>(
        srcA, aud_kpm, vid_ln_g + (size_t)i * DD, vid_ln_b + (size_t)i * DD, partial);
    reduce_nsum_kernel<<<BB * 8, 256, 0, stream>>>(partial, aud_kpm, nsum, fac, flg);
    ksum_kernel<<<BB * DD / 4, 256, 0, stream>>>(nsum, Wk_aud_for_vid + (size_t)i * WW, ks);
    m_kernel<<<BB * HH, 256, 0, stream>>>(ks, fac, Wq_vid + (size_t)i * WW, m);
    update_kernel<<<(BB * TT) / 4, 256, 0, stream>>>(
        srcV, vid_ln_g + (size_t)i * DD, vid_ln_b + (size_t)i * DD, m, flg,
        vg_W1 + (size_t)i * 16 * HH, vg_b1 + (size_t)i * 16,
        vg_W2 + (size_t)i * 16, vg_b2 + i, xv);

    // --- Phase B: aud gated by attn to UPDATED vid; aud_ln on BOTH sides ---
    ln_masked_sum_kernel<<<BB * NT, 256, 0, stream>>>(
        xv, vid_kpm, aud_ln_g + (size_t)i * DD, aud_ln_b + (size_t)i * DD, partial);
    reduce_nsum_kernel<<<BB * 8, 256, 0, stream>>>(partial, vid_kpm, nsum, fac, flg);
    ksum_kernel<<<BB * DD / 4, 256, 0, stream>>>(nsum, Wk_vid_for_aud + (size_t)i * WW, ks);
    m_kernel<<<BB * HH, 256, 0, stream>>>(ks, fac, Wq_aud + (size_t)i * WW, m);
    update_kernel<<<(BB * TT) / 4, 256, 0, stream>>>(
        srcA, aud_ln_g + (size_t)i * DD, aud_ln_b + (size_t)i * DD, m, flg,
        ag_W1 + (size_t)i * 16 * HH, ag_b1 + (size_t)i * 16,
        ag_W2 + (size_t)i * 16, ag_b2 + i, xa);
  }
}